// Round 6
// baseline (447.196 us; speedup 1.0000x reference)
//
#include <hip/hip_runtime.h>
#include <hip/hip_fp16.h>
#include <math.h>

#define NHEADS 12
#define SEQ 4096
#define BATCH 8

typedef _Float16 half8 __attribute__((ext_vector_type(8)));
typedef float floatx4 __attribute__((ext_vector_type(4)));

// ---------------- zero small accumulators ----------------
__global__ void zero_kernel(float* p, int n) {
  int i = blockIdx.x * 256 + threadIdx.x;
  if (i < n) p[i] = 0.f;
}

// ---------------- fp32 -> fp16 cast, 4 elems/thread ----------------
__global__ void cast_f2h(const float* __restrict__ in, __half* __restrict__ out, int n) {
  int i = (blockIdx.x * 256 + threadIdx.x) * 4;
  if (i < n) {
    float4 v = *(const float4*)&in[i];
    ushort4 o;
    o.x = __half_as_ushort(__float2half(v.x));
    o.y = __half_as_ushort(__float2half(v.y));
    o.z = __half_as_ushort(__float2half(v.z));
    o.w = __half_as_ushort(__float2half(v.w));
    *(ushort4*)&out[i] = o;
  }
}

// ---- raw 16B global->LDS (dst must be wave-uniform; g carries swizzle) ----
__device__ __forceinline__ void gld16(const __half* g, _Float16* dst) {
  __builtin_amdgcn_global_load_lds((const __attribute__((address_space(1))) void*)g,
                                   (__attribute__((address_space(3))) void*)dst, 16, 0, 0);
}

// fragment LDS offset (halfs) for the staged XOR-swizzle layout
__device__ __forceinline__ int fragoff(int row, int quad) {
  const int mp = row >> 1;
  const int p  = ((row & 1) << 2) | quad;
  return (mp * 8 + (p ^ (mp & 7))) * 8;
}

// ---- L64: 64x64 f16 tile, row-major with XOR swizzle on 16B chunks ----
__device__ __forceinline__ void write_l64(_Float16* lds, int row, int col, float v) {
  lds[row * 64 + ((((col >> 3) ^ (row & 7))) << 3) + (col & 7)] = (_Float16)v;
}
__device__ __forceinline__ half8 read_l64c(const _Float16* lds, int row, int c) {
  return *(const half8*)(lds + row * 64 + ((c ^ (row & 7)) << 3));
}

__device__ __forceinline__ void barrier_raw() {
  asm volatile("s_barrier" ::: "memory");
}

// ====== KV HGEMM: 256x256, 4-deep ring, phase-split (R5 schedule) with
// hoisted addressing: per-thread swizzled global pointers + 12 precomputed
// fragment offsets. Schedule/barriers/vmcnt identical to R5 (race-verified).
// Transposed (b,h,d,n) k/v emit.
__global__ __launch_bounds__(512, 2) void hgemm_kv8_kernel(
    const __half* __restrict__ A, const __half* __restrict__ W,
    const float* __restrict__ bias,
    __half* __restrict__ outK, __half* __restrict__ outV)
{
  const int K = 768;
  const int NT = 24;                       // 768 / 32
  extern __shared__ __align__(16) _Float16 sh[];   // 4 bufs x 16384 halfs = 128KB
  const int t    = threadIdx.x;
  const int w    = t >> 6;
  const int l    = t & 63;
  const int quad = l >> 4;
  const int mrow = l & 15;
  const int wm   = w >> 2;                 // 0..1 (M)
  const int wn   = w & 3;                  // 0..3 (N)

  // XCD-aware, A-reuse-major: j innermost per XCD chunk (FETCH-proven in R2)
  const int bid  = blockIdx.x;
  const int xcd  = bid & 7;
  const int ii   = bid >> 3;               // 0..95
  const int mg   = ii / 6;                 // 0..15
  const int jj   = ii - mg * 6;            // 0..5
  const int m0   = (xcd * 16 + mg) * 256;
  const int j0   = jj * 256;

  // ---- hoisted stage addressing (was recomputed 4x/iter) ----
  const int mp  = t >> 3;
  const int pp  = (t & 7) ^ (mp & 7);
  const int rsw = mp * 2 + (pp >> 2);
  const int qsw = (pp & 3) * 8;
  const __half* gA0 = A + (size_t)(m0 + rsw) * K + qsw;
  const __half* gA1 = gA0 + (size_t)128 * K;
  const __half* gW0 = W + (size_t)(768 + j0 + rsw) * K + qsw;
  const __half* gW1 = gW0 + (size_t)128 * K;
  const int ld = (t >> 6) * 512;           // wave-uniform LDS dst (halfs)

  // ---- hoisted fragment offsets (halfs, slot-local) ----
  int aoff[8], boff[4];
#pragma unroll
  for (int i = 0; i < 8; ++i)
    aoff[i] = wm * 4096 + fragoff(i * 16 + mrow, quad);
#pragma unroll
  for (int j = 0; j < 4; ++j) {
    const int C = wn * 64 + j * 16 + mrow;
    boff[j] = 8192 + (C >> 7) * 4096 + fragoff(C & 127, quad);
  }

  floatx4 acc[8][4];
#pragma unroll
  for (int i = 0; i < 8; ++i)
#pragma unroll
    for (int j = 0; j < 4; ++j) acc[i][j] = (floatx4){0.f, 0.f, 0.f, 0.f};

  // prologue: stage K-tiles 0,1,2 into bufs 0,1,2
#pragma unroll
  for (int kt = 0; kt < 3; ++kt) {
    _Float16* db = sh + kt * 16384;
    const int kg = kt * 32;
    gld16(gA0 + kg, db + ld);
    gld16(gA1 + kg, db + 4096 + ld);
    gld16(gW0 + kg, db + 8192 + ld);
    gld16(gW1 + kg, db + 12288 + ld);
  }
  asm volatile("s_waitcnt vmcnt(8)" ::: "memory");   // K-tile 0 landed
  barrier_raw();

#pragma unroll 4
  for (int kt = 0; kt < NT; ++kt) {
    const _Float16* bb = sh + (kt & 3) * 16384;
    const bool st = (kt + 3 < NT);
    _Float16* db = sh + ((kt + 3) & 3) * 16384;
    const int kg = (kt + 3) * 32;
    half8 af[4], bf[4];

    // ---- phase 0: B frags + A rows 0..63, stage A halves ----
#pragma unroll
    for (int j = 0; j < 4; ++j) bf[j] = *(const half8*)(bb + boff[j]);
#pragma unroll
    for (int i = 0; i < 4; ++i) af[i] = *(const half8*)(bb + aoff[i]);
    if (st) {
      gld16(gA0 + kg, db + ld);
      gld16(gA1 + kg, db + 4096 + ld);
    }
    barrier_raw();
    __builtin_amdgcn_s_setprio(1);
#pragma unroll
    for (int i = 0; i < 4; ++i)
#pragma unroll
      for (int j = 0; j < 4; ++j)
        acc[i][j] = __builtin_amdgcn_mfma_f32_16x16x32_f16(af[i], bf[j], acc[i][j], 0, 0, 0);
    __builtin_amdgcn_s_setprio(0);

    // ---- phase 1: A rows 64..127, stage W halves ----
#pragma unroll
    for (int i = 0; i < 4; ++i) af[i] = *(const half8*)(bb + aoff[i + 4]);
    if (st) {
      gld16(gW0 + kg, db + 8192 + ld);
      gld16(gW1 + kg, db + 12288 + ld);
    }
    barrier_raw();
    __builtin_amdgcn_s_setprio(1);
#pragma unroll
    for (int i = 0; i < 4; ++i)
#pragma unroll
      for (int j = 0; j < 4; ++j)
        acc[i + 4][j] = __builtin_amdgcn_mfma_f32_16x16x32_f16(af[i], bf[j], acc[i + 4][j], 0, 0, 0);
    __builtin_amdgcn_s_setprio(0);

    // ---- K-tile end: counted drain (tile kt+1 fully landed) ----
    if (kt < NT - 3)       asm volatile("s_waitcnt vmcnt(8)" ::: "memory");
    else if (kt == NT - 3) asm volatile("s_waitcnt vmcnt(4)" ::: "memory");
    else if (kt == NT - 2) asm volatile("s_waitcnt vmcnt(0)" ::: "memory");
    barrier_raw();
  }

  // epilogue: wave tile = 128 rows(n) x one head's 64 cols(d) of k or v.
  // TRANSPOSED emit: scratch (d, n), global layout (b,h,d,n).
  const int col0 = 768 + j0 + wn * 64;
  const int t3   = col0 / 768;                 // 1=k, 2=v
  const int h    = (col0 - t3 * 768) >> 6;
  __half* dst    = (t3 == 1) ? outK : outV;
  const int m0w  = m0 + wm * 128;
  const int b_   = m0w >> 12;
  const int n0w  = m0w & 4095;
  _Float16* scr  = sh + w * 4096;              // 8KB per wave
  const size_t gbT = (size_t)(b_ * NHEADS + h) * 64 * 4096;

#pragma unroll
  for (int hf = 0; hf < 2; ++hf) {
#pragma unroll
    for (int j = 0; j < 4; ++j) {
      const int col = j * 16 + mrow;           // d
      const float bsv = bias[col0 + col];
#pragma unroll
      for (int ii2 = 0; ii2 < 4; ++ii2)
#pragma unroll
        for (int r = 0; r < 4; ++r) {
          const int row = ii2 * 16 + quad * 4 + r;   // n-local
          float val = acc[hf * 4 + ii2][j][r] + bsv;
          if (t3 == 1) val = (val > 0.f) ? (val + 1.f) : expf(val);  // elu+1
          write_l64(scr, col, row, val);             // (d, n)
        }
    }
    barrier_raw();
#pragma unroll
    for (int it = 0; it < 8; ++it) {
      const int dd = it * 8 + (l >> 3);
      const int c  = l & 7;
      half8 vv = read_l64c(scr, dd, c);
      *(half8*)((_Float16*)dst + gbT + (size_t)dd * 4096 + n0w + hf * 64 + c * 8) = vv;
    }
    barrier_raw();
  }
}

// ====== proj HGEMM: 128x128 tile, 256 thr / 4 waves (2x2), 3-deep ring,
// counted vmcnt(4), 3 blocks/CU (48KB LDS), hoisted addressing.
__global__ __launch_bounds__(256, 3) void hgemm_proj_kernel(
    const __half* __restrict__ A, const __half* __restrict__ W,
    const float* __restrict__ bias, float* __restrict__ outF)
{
  const int K = 768;
  const int NT = 24;
  __shared__ __align__(16) _Float16 sh[3 * 8192];   // 48KB: 3 slots x (A | B)
  const int t    = threadIdx.x;
  const int w    = t >> 6;
  const int l    = t & 63;
  const int quad = l >> 4;
  const int mrow = l & 15;
  const int wr   = (w >> 1) * 64;
  const int wc   = (w & 1) * 64;

  const int bid  = blockIdx.x;
  const int xcd  = bid & 7;
  const int ii   = bid >> 3;               // 0..191
  const int mg   = ii / 6;                 // 0..31
  const int jj   = ii - mg * 6;            // 0..5
  const int m0   = (xcd * 32 + mg) * 128;
  const int j0   = jj * 128;

  // hoisted stage addressing (two load slots per operand, 256 threads)
  const int s1  = 256 + t;
  const int mpa = t >> 3,  ppa = (t & 7) ^ (mpa & 7);
  const int ra  = mpa * 2 + (ppa >> 2), qa = (ppa & 3) * 8;
  const int mpb = s1 >> 3, ppb = (s1 & 7) ^ (mpb & 7);
  const int rb  = mpb * 2 + (ppb >> 2), qb = (ppb & 3) * 8;
  const int lda_ = (t >> 6) * 512;          // wave-uniform
  const int ldb_ = (s1 >> 6) * 512;
  const __half* gA_0 = A + (size_t)(m0 + ra) * K + qa;
  const __half* gA_1 = A + (size_t)(m0 + rb) * K + qb;
  const __half* gB_0 = W + (size_t)(j0 + ra) * K + qa;
  const __half* gB_1 = W + (size_t)(j0 + rb) * K + qb;

  int aoff[4], boff[4];
#pragma unroll
  for (int i = 0; i < 4; ++i) aoff[i] = fragoff(wr + i * 16 + mrow, quad);
#pragma unroll
  for (int j = 0; j < 4; ++j) boff[j] = 4096 + fragoff(wc + j * 16 + mrow, quad);

  floatx4 acc[4][4];
#pragma unroll
  for (int i = 0; i < 4; ++i)
#pragma unroll
    for (int j = 0; j < 4; ++j) acc[i][j] = (floatx4){0.f, 0.f, 0.f, 0.f};

  // prologue: stage tiles 0,1 into slots 0,1 (4 loads/thread per tile)
  gld16(gA_0, sh + lda_);           gld16(gA_1, sh + ldb_);
  gld16(gB_0, sh + 4096 + lda_);    gld16(gB_1, sh + 4096 + ldb_);
  gld16(gA_0 + 32, sh + 8192 + lda_);        gld16(gA_1 + 32, sh + 8192 + ldb_);
  gld16(gB_0 + 32, sh + 12288 + lda_);       gld16(gB_1 + 32, sh + 12288 + ldb_);
  asm volatile("s_waitcnt vmcnt(4)" ::: "memory");   // tile 0 landed
  barrier_raw();

  int cur = 0, nxt = 2;                    // slot indices (mod 3)
#pragma unroll 3
  for (int kt = 0; kt < NT; ++kt) {
    const _Float16* bb = sh + cur * 8192;
    _Float16* db = sh + nxt * 8192;
    const bool st = (kt + 2 < NT);
    const int kg = (kt + 2) * 32;

    if (st) {
      gld16(gA_0 + kg, db + lda_);        gld16(gA_1 + kg, db + ldb_);
      gld16(gB_0 + kg, db + 4096 + lda_); gld16(gB_1 + kg, db + 4096 + ldb_);
    }
    half8 af[4], bf[4];
#pragma unroll
    for (int i = 0; i < 4; ++i) af[i] = *(const half8*)(bb + aoff[i]);
#pragma unroll
    for (int j = 0; j < 4; ++j) bf[j] = *(const half8*)(bb + boff[j]);
#pragma unroll
    for (int i = 0; i < 4; ++i)
#pragma unroll
      for (int j = 0; j < 4; ++j)
        acc[i][j] = __builtin_amdgcn_mfma_f32_16x16x32_f16(af[i], bf[j], acc[i][j], 0, 0, 0);

    if (kt < NT - 2)       asm volatile("s_waitcnt vmcnt(4)" ::: "memory");
    else if (kt == NT - 2) asm volatile("s_waitcnt vmcnt(0)" ::: "memory");
    barrier_raw();
    cur = (cur + 1) % 3;
    nxt = (nxt + 1) % 3;
  }

  // fp32 row-major out: 16 lanes x 4B = 64B segments, no RMW
#pragma unroll
  for (int j = 0; j < 4; ++j) {
    const int col = j0 + wc + j * 16 + mrow;
    const float bsv = bias[col];
#pragma unroll
    for (int i = 0; i < 4; ++i)
#pragma unroll
      for (int r = 0; r < 4; ++r) {
        const int m = m0 + wr + i * 16 + quad * 4 + r;
        outF[(size_t)m * 768 + col] = acc[i][j][r] + bsv;
      }
  }
}

// ============ kv via MFMA on transposed k,v: no LDS staging ============
__global__ __launch_bounds__(256) void kv_mfma_kernel(
    const __half* __restrict__ kT, const __half* __restrict__ vT,
    float* __restrict__ kv, float* __restrict__ ksum)
{
  extern __shared__ float red[];               // 4*4096 + 4*64 floats = 66.5KB
  float* ksr = red + 4 * 4096;
  const int bh = blockIdx.x;                   // 0..95
  const int sp = blockIdx.y;                   // 0..3
  const int t  = threadIdx.x;
  const int w  = t >> 6;
  const int l  = t & 63;
  const int quad = l >> 4;
  const int mrow = l & 15;
  const size_t base = (size_t)bh * 64 * 4096;
  const int n0 = sp * 1024 + w * 256;

  floatx4 acc[4][4];
  floatx4 ks[4];
#pragma unroll
  for (int i = 0; i < 4; ++i) {
    ks[i] = (floatx4){0.f, 0.f, 0.f, 0.f};
#pragma unroll
    for (int j = 0; j < 4; ++j) acc[i][j] = (floatx4){0.f, 0.f, 0.f, 0.f};
  }
  half8 ones;
#pragma unroll
  for (int e = 0; e < 8; ++e) ones[e] = (_Float16)1.0f;

  const __half* pk[4];
  const __half* pv[4];
#pragma unroll
  for (int i = 0; i < 4; ++i) {
    pk[i] = kT + base + (size_t)(i * 16 + mrow) * 4096 + n0 + quad * 8;
    pv[i] = vT + base + (size_t)(i * 16 + mrow) * 4096 + n0 + quad * 8;
  }

#pragma unroll
  for (int nn = 0; nn < 256; nn += 32) {
    half8 af[4], bf[4];
#pragma unroll
    for (int i = 0; i < 4; ++i) af[i] = *(const half8*)(pk[i] + nn);
#pragma unroll
    for (int j = 0; j < 4; ++j) bf[j] = *(const half8*)(pv[j] + nn);
#pragma unroll
    for (int i = 0; i < 4; ++i)
#pragma unroll
      for (int j = 0; j < 4; ++j)
        acc[i][j] = __builtin_amdgcn_mfma_f32_16x16x32_f16(af[i], bf[j], acc[i][j], 0, 0, 0);
#pragma unroll
    for (int i = 0; i < 4; ++i)
      ks[i] = __builtin_amdgcn_mfma_f32_16x16x32_f16(af[i], ones, ks[i], 0, 0, 0);
  }

  float* rw = red + w * 4096;
#pragma unroll
  for (int i = 0; i < 4; ++i)
#pragma unroll
    for (int j = 0; j < 4; ++j)
#pragma unroll
      for (int r = 0; r < 4; ++r)
        rw[(i * 16 + quad * 4 + r) * 64 + j * 16 + mrow] = acc[i][j][r];
  if (mrow == 0) {
#pragma unroll
    for (int i = 0; i < 4; ++i)
#pragma unroll
      for (int r = 0; r < 4; ++r)
        ksr[w * 64 + i * 16 + quad * 4 + r] = ks[i][r];
  }
  __syncthreads();
#pragma unroll
  for (int ii = 0; ii < 16; ++ii) {
    const int idx = ii * 256 + t;
    const float s = red[idx] + red[4096 + idx] + red[8192 + idx] + red[12288 + idx];
    atomicAdd(&kv[(size_t)bh * 4096 + idx], s);
  }
  if (t < 64)
    atomicAdd(&ksum[(size_t)bh * 64 + t], ksr[t] + ksr[64 + t] + ksr[128 + t] + ksr[192 + t]);
}

// ------- fused Q-GEMM + attention apply (dbuf main loop + hoisted addr) ----
__global__ __launch_bounds__(256) void qattn_kernel(
    const __half* __restrict__ A, const __half* __restrict__ W,
    const float* __restrict__ bias,
    const float* __restrict__ kvg, const float* __restrict__ ksumg,
    __half* __restrict__ att)
{
  const int K = 768;
  const int NT = 24;
  __shared__ __align__(16) _Float16 sh[24576];  // 48 KB: dbuf [0,16384) | kvT [16384,24576)
  __shared__ float norms[256];
  __shared__ float ksums[128];
  const int t    = threadIdx.x;
  const int w    = t >> 6;
  const int l    = t & 63;
  const int quad = l >> 4;
  const int mrow = l & 15;
  const int m0   = blockIdx.x * 128;
  const int j0   = blockIdx.y * 128;
  const int wr   = (w >> 1) * 64;
  const int wc   = (w & 1) * 64;
  const int b_   = m0 >> 12;
  const int h0   = j0 >> 6;

  // stage kvT (f16, L64, [e][d]) + ksum for the 2 heads
  {
    _Float16* kvT0 = sh + 16384;
#pragma unroll
    for (int ii = 0; ii < 32; ++ii) {
      const int gidx = ii * 256 + t;
      const int head = gidx >> 12;
      const int r    = gidx & 4095;
      const float val = kvg[(size_t)(b_ * NHEADS + h0 + head) * 4096 + r];
      write_l64(kvT0 + head * 4096, r & 63, r >> 6, val);
    }
    if (t < 128) ksums[t] = ksumg[(size_t)(b_ * NHEADS + h0 + (t >> 6)) * 64 + (t & 63)];
  }

  // hoisted stage addressing (two load slots per operand)
  const int s1  = 256 + t;
  const int mpa = t >> 3,  ppa = (t & 7) ^ (mpa & 7);
  const int ra  = mpa * 2 + (ppa >> 2), qa = (ppa & 3) * 8;
  const int mpb = s1 >> 3, ppb = (s1 & 7) ^ (mpb & 7);
  const int rb  = mpb * 2 + (ppb >> 2), qb = (ppb & 3) * 8;
  const int lda_ = (t >> 6) * 512;
  const int ldb_ = (s1 >> 6) * 512;
  const __half* gA_0 = A + (size_t)(m0 + ra) * K + qa;
  const __half* gA_1 = A + (size_t)(m0 + rb) * K + qb;
  const __half* gB_0 = W + (size_t)(j0 + ra) * K + qa;
  const __half* gB_1 = W + (size_t)(j0 + rb) * K + qb;

  int aoff[4], boff[4];
#pragma unroll
  for (int i = 0; i < 4; ++i) aoff[i] = fragoff(wr + i * 16 + mrow, quad);
#pragma unroll
  for (int j = 0; j < 4; ++j) boff[j] = 4096 + fragoff(wc + j * 16 + mrow, quad);

  floatx4 acc[4][4];
#pragma unroll
  for (int i = 0; i < 4; ++i)
#pragma unroll
    for (int j = 0; j < 4; ++j) acc[i][j] = (floatx4){0.f, 0.f, 0.f, 0.f};

  // prologue: stage tile 0 into slot 0
  gld16(gA_0, sh + lda_);         gld16(gA_1, sh + ldb_);
  gld16(gB_0, sh + 4096 + lda_);  gld16(gB_1, sh + 4096 + ldb_);
  asm volatile("s_waitcnt vmcnt(0)" ::: "memory");
  barrier_raw();

#pragma unroll 2
  for (int kt = 0; kt < NT; ++kt) {
    const _Float16* bb = sh + (kt & 1) * 8192;
    _Float16* db = sh + ((kt + 1) & 1) * 8192;
    const bool st = (kt + 1 < NT);
    const int kg = (kt + 1) * 32;

    if (st) {
      gld16(gA_0 + kg, db + lda_);        gld16(gA_1 + kg, db + ldb_);
      gld16(gB_0 + kg, db + 4096 + lda_); gld16(gB_1 + kg, db + 4096 + ldb_);
    }
    half8 af[4], bf[4];
#pragma unroll
    for (int i = 0; i < 4; ++i) af[i] = *(const half8*)(bb + aoff[i]);
#pragma unroll
    for (int j = 0; j < 4; ++j) bf[j] = *(const half8*)(bb + boff[j]);
#pragma unroll
    for (int i = 0; i < 4; ++i)
#pragma unroll
      for (int j = 0; j < 4; ++j)
        acc[i][j] = __builtin_amdgcn_mfma_f32_16x16x32_f16(af[i], bf[j], acc[i][j], 0, 0, 0);

    if (st) asm volatile("s_waitcnt vmcnt(0)" ::: "memory");
    barrier_raw();
  }

  _Float16* qtile = sh + w * 4096;
  const _Float16* kvT = sh + 16384 + (w & 1) * 4096;
  const int hh = w & 1;

  __syncthreads();
  // phase 1: q = elu(acc+bias)+1 -> f16 L64
#pragma unroll
  for (int j = 0; j < 4; ++j) {
    const int col = j * 16 + mrow;
    const float bsv = bias[j0 + wc + col];
#pragma unroll
    for (int i = 0; i < 4; ++i)
#pragma unroll
      for (int r = 0; r < 4; ++r) {
        const int row = i * 16 + quad * 4 + r;
        float val = acc[i][j][r] + bsv;
        val = (val > 0.f) ? (val + 1.f) : expf(val);
        write_l64(qtile, row, col, val);
      }
  }
  __syncthreads();

  // phase 2: reciprocal normalizer per row
  {
    float nrm = 0.f;
#pragma unroll
    for (int c = 0; c < 8; ++c) {
      half8 qv = read_l64c(qtile, l, c);
#pragma unroll
      for (int e = 0; e < 8; ++e) nrm += (float)qv[e] * ksums[hh * 64 + c * 8 + e];
    }
    norms[w * 64 + l] = 1.f / (nrm + 1e-6f);
  }

  // phase 3: att = q @ kvT^T
  floatx4 oacc[4][4];
#pragma unroll
  for (int i = 0; i < 4; ++i)
#pragma unroll
    for (int j = 0; j < 4; ++j) oacc[i][j] = (floatx4){0.f, 0.f, 0.f, 0.f};
#pragma unroll
  for (int ks = 0; ks < 2; ++ks) {
    half8 af[4], bf[4];
#pragma unroll
    for (int i = 0; i < 4; ++i) af[i] = read_l64c(qtile, i * 16 + mrow, ks * 4 + quad);
#pragma unroll
    for (int j = 0; j < 4; ++j) bf[j] = read_l64c(kvT, j * 16 + mrow, ks * 4 + quad);
#pragma unroll
    for (int i = 0; i < 4; ++i)
#pragma unroll
      for (int j = 0; j < 4; ++j)
        oacc[i][j] = __builtin_amdgcn_mfma_f32_16x16x32_f16(af[i], bf[j], oacc[i][j], 0, 0, 0);
  }
  __syncthreads();

  // phase 4: scale by 1/norm, transpose via qtile, coalesced store
#pragma unroll
  for (int i = 0; i < 4; ++i)
#pragma unroll
    for (int r = 0; r < 4; ++r) {
      const int row = i * 16 + quad * 4 + r;
      const float rn = norms[w * 64 + row];
#pragma unroll
      for (int j = 0; j < 4; ++j)
        write_l64(qtile, row, j * 16 + mrow, oacc[i][j][r] * rn);
    }
  __syncthreads();
  const int n0w = (m0 & 4095) + wr;
  const size_t abase = (size_t)(b_ * SEQ + n0w) * 768 + (h0 + hh) * 64;
#pragma unroll
  for (int it = 0; it < 8; ++it) {
    const int row = it * 8 + (l >> 3);
    const int c   = l & 7;
    half8 vv = read_l64c(qtile, row, c);
    *(half8*)((_Float16*)att + abase + (size_t)row * 768 + c * 8) = vv;
  }
}

extern "C" void kernel_launch(void* const* d_in, const int* in_sizes, int n_in,
                              void* d_out, int out_size, void* d_ws, size_t ws_size,
                              hipStream_t stream)
{
  const float* x     = (const float*)d_in[0];
  const float* Wqkv  = (const float*)d_in[1];
  const float* bqkv  = (const float*)d_in[2];
  const float* Wproj = (const float*)d_in[3];
  const float* bproj = (const float*)d_in[4];
  float* out = (float*)d_out;

  const size_t SZ = (size_t)BATCH * NHEADS * SEQ * 64;  // 25,165,824
  __half* xh  = (__half*)d_ws;
  __half* Wqh = xh + SZ;
  __half* Wph = Wqh + (size_t)2304 * 768;
  __half* R3  = Wph + (size_t)768 * 768;   // kT -> att
  __half* R4  = R3 + SZ;                   // vT
  float*  kvb = (float*)(R4 + SZ);
  float*  ksum = kvb + 96 * 64 * 64;

  static bool attr_set = false;
  if (!attr_set) {
    hipFuncSetAttribute((const void*)hgemm_kv8_kernel,
                        hipFuncAttributeMaxDynamicSharedMemorySize, 131072);
    hipFuncSetAttribute((const void*)kv_mfma_kernel,
                        hipFuncAttributeMaxDynamicSharedMemorySize, 66560);
    attr_set = true;
  }

  zero_kernel<<<1560, 256, 0, stream>>>(kvb, 96 * 64 * 64 + 96 * 64);

  cast_f2h<<<(int)(SZ / 1024), 256, 0, stream>>>(x, xh, (int)SZ);
  cast_f2h<<<(2304 * 768) / 1024, 256, 0, stream>>>(Wqkv, Wqh, 2304 * 768);
  cast_f2h<<<(768 * 768) / 1024, 256, 0, stream>>>(Wproj, Wph, 768 * 768);

  // K,V columns [768, 2304): kT -> R3, vT -> R4, layout (b,h,d,n).
  hgemm_kv8_kernel<<<768, 512, 131072, stream>>>(xh, Wqh, bqkv, R3, R4);

  // kv + ksum via MFMA on the transposed layout
  kv_mfma_kernel<<<dim3(96, 4), 256, 66560, stream>>>(R3, R4, kvb, ksum);

  // fused Q-GEMM + attention: att -> R3 (kT dead after kv_mfma_kernel)
  qattn_kernel<<<dim3(256, 6), 256, 0, stream>>>(
      xh, Wqh, bqkv, kvb, ksum, R3);

  // output projection: fp32 out, 128x128 3-ring, 3 blk/CU, 1536 blocks
  hgemm_proj_kernel<<<1536, 256, 0, stream>>>(R3, Wph, bproj, out);
}

// Round 7
// 442.564 us; speedup vs baseline: 1.0105x; 1.0105x over previous
//
#include <hip/hip_runtime.h>
#include <hip/hip_fp16.h>
#include <math.h>

#define NHEADS 12
#define SEQ 4096
#define BATCH 8

typedef _Float16 half8 __attribute__((ext_vector_type(8)));
typedef float floatx4 __attribute__((ext_vector_type(4)));

// ---------------- zero small accumulators ----------------
__global__ void zero_kernel(float* p, int n) {
  int i = blockIdx.x * 256 + threadIdx.x;
  if (i < n) p[i] = 0.f;
}

// ---------------- fp32 -> fp16 cast, 4 elems/thread ----------------
__global__ void cast_f2h(const float* __restrict__ in, __half* __restrict__ out, int n) {
  int i = (blockIdx.x * 256 + threadIdx.x) * 4;
  if (i < n) {
    float4 v = *(const float4*)&in[i];
    ushort4 o;
    o.x = __half_as_ushort(__float2half(v.x));
    o.y = __half_as_ushort(__float2half(v.y));
    o.z = __half_as_ushort(__float2half(v.z));
    o.w = __half_as_ushort(__float2half(v.w));
    *(ushort4*)&out[i] = o;
  }
}

// ---- raw 16B global->LDS (dst must be wave-uniform; g carries swizzle) ----
__device__ __forceinline__ void gld16(const __half* g, _Float16* dst) {
  __builtin_amdgcn_global_load_lds((const __attribute__((address_space(1))) void*)g,
                                   (__attribute__((address_space(3))) void*)dst, 16, 0, 0);
}

// fragment LDS offset (halfs) for the staged XOR-swizzle layout
__device__ __forceinline__ int fragoff(int row, int quad) {
  const int mp = row >> 1;
  const int p  = ((row & 1) << 2) | quad;
  return (mp * 8 + (p ^ (mp & 7))) * 8;
}

// ---- 128x32 f16 staging tile via global_load_lds (16B), 256-thr version ----
__device__ __forceinline__ void stage_tile(const __half* __restrict__ gbase, int ldg,
                                           _Float16* lds, int t) {
#pragma unroll
  for (int it = 0; it < 2; ++it) {
    const int s  = it * 256 + t;
    const int mp = s >> 3, ps = s & 7;
    const int p  = ps ^ (mp & 7);
    const int r  = mp * 2 + (p >> 2);
    const int q  = p & 3;
    const __half* g = gbase + (size_t)r * ldg + q * 8;
    _Float16* dst = lds + (s >> 6) * 512;
    gld16(g, dst);
  }
}

// ---- L64: 64x64 f16 tile, row-major with XOR swizzle on 16B chunks ----
__device__ __forceinline__ void write_l64(_Float16* lds, int row, int col, float v) {
  lds[row * 64 + ((((col >> 3) ^ (row & 7))) << 3) + (col & 7)] = (_Float16)v;
}
__device__ __forceinline__ half8 read_l64c(const _Float16* lds, int row, int c) {
  return *(const half8*)(lds + row * 64 + ((c ^ (row & 7)) << 3));
}

__device__ __forceinline__ void barrier_raw() {
  asm volatile("s_barrier" ::: "memory");
}

// ====== KV HGEMM: 256x256, 4-deep ring, phase-split, hoisted addressing.
// (R6 kernel, unchanged - control.) Transposed (b,h,d,n) k/v emit.
__global__ __launch_bounds__(512, 2) void hgemm_kv8_kernel(
    const __half* __restrict__ A, const __half* __restrict__ W,
    const float* __restrict__ bias,
    __half* __restrict__ outK, __half* __restrict__ outV)
{
  const int K = 768;
  const int NT = 24;                       // 768 / 32
  extern __shared__ __align__(16) _Float16 sh[];   // 4 bufs x 16384 halfs = 128KB
  const int t    = threadIdx.x;
  const int w    = t >> 6;
  const int l    = t & 63;
  const int quad = l >> 4;
  const int mrow = l & 15;
  const int wm   = w >> 2;                 // 0..1 (M)
  const int wn   = w & 3;                  // 0..3 (N)

  const int bid  = blockIdx.x;
  const int xcd  = bid & 7;
  const int ii   = bid >> 3;               // 0..95
  const int mg   = ii / 6;                 // 0..15
  const int jj   = ii - mg * 6;            // 0..5
  const int m0   = (xcd * 16 + mg) * 256;
  const int j0   = jj * 256;

  // hoisted stage addressing
  const int mp  = t >> 3;
  const int pp  = (t & 7) ^ (mp & 7);
  const int rsw = mp * 2 + (pp >> 2);
  const int qsw = (pp & 3) * 8;
  const __half* gA0 = A + (size_t)(m0 + rsw) * K + qsw;
  const __half* gA1 = gA0 + (size_t)128 * K;
  const __half* gW0 = W + (size_t)(768 + j0 + rsw) * K + qsw;
  const __half* gW1 = gW0 + (size_t)128 * K;
  const int ld = (t >> 6) * 512;           // wave-uniform LDS dst (halfs)

  int aoff[8], boff[4];
#pragma unroll
  for (int i = 0; i < 8; ++i)
    aoff[i] = wm * 4096 + fragoff(i * 16 + mrow, quad);
#pragma unroll
  for (int j = 0; j < 4; ++j) {
    const int C = wn * 64 + j * 16 + mrow;
    boff[j] = 8192 + (C >> 7) * 4096 + fragoff(C & 127, quad);
  }

  floatx4 acc[8][4];
#pragma unroll
  for (int i = 0; i < 8; ++i)
#pragma unroll
    for (int j = 0; j < 4; ++j) acc[i][j] = (floatx4){0.f, 0.f, 0.f, 0.f};

#pragma unroll
  for (int kt = 0; kt < 3; ++kt) {
    _Float16* db = sh + kt * 16384;
    const int kg = kt * 32;
    gld16(gA0 + kg, db + ld);
    gld16(gA1 + kg, db + 4096 + ld);
    gld16(gW0 + kg, db + 8192 + ld);
    gld16(gW1 + kg, db + 12288 + ld);
  }
  asm volatile("s_waitcnt vmcnt(8)" ::: "memory");   // K-tile 0 landed
  barrier_raw();

#pragma unroll 4
  for (int kt = 0; kt < NT; ++kt) {
    const _Float16* bb = sh + (kt & 3) * 16384;
    const bool st = (kt + 3 < NT);
    _Float16* db = sh + ((kt + 3) & 3) * 16384;
    const int kg = (kt + 3) * 32;
    half8 af[4], bf[4];

    // ---- phase 0: B frags + A rows 0..63, stage A halves ----
#pragma unroll
    for (int j = 0; j < 4; ++j) bf[j] = *(const half8*)(bb + boff[j]);
#pragma unroll
    for (int i = 0; i < 4; ++i) af[i] = *(const half8*)(bb + aoff[i]);
    if (st) {
      gld16(gA0 + kg, db + ld);
      gld16(gA1 + kg, db + 4096 + ld);
    }
    barrier_raw();
    __builtin_amdgcn_s_setprio(1);
#pragma unroll
    for (int i = 0; i < 4; ++i)
#pragma unroll
      for (int j = 0; j < 4; ++j)
        acc[i][j] = __builtin_amdgcn_mfma_f32_16x16x32_f16(af[i], bf[j], acc[i][j], 0, 0, 0);
    __builtin_amdgcn_s_setprio(0);

    // ---- phase 1: A rows 64..127, stage W halves ----
#pragma unroll
    for (int i = 0; i < 4; ++i) af[i] = *(const half8*)(bb + aoff[i + 4]);
    if (st) {
      gld16(gW0 + kg, db + 8192 + ld);
      gld16(gW1 + kg, db + 12288 + ld);
    }
    barrier_raw();
    __builtin_amdgcn_s_setprio(1);
#pragma unroll
    for (int i = 0; i < 4; ++i)
#pragma unroll
      for (int j = 0; j < 4; ++j)
        acc[i + 4][j] = __builtin_amdgcn_mfma_f32_16x16x32_f16(af[i], bf[j], acc[i + 4][j], 0, 0, 0);
    __builtin_amdgcn_s_setprio(0);

    if (kt < NT - 3)       asm volatile("s_waitcnt vmcnt(8)" ::: "memory");
    else if (kt == NT - 3) asm volatile("s_waitcnt vmcnt(4)" ::: "memory");
    else if (kt == NT - 2) asm volatile("s_waitcnt vmcnt(0)" ::: "memory");
    barrier_raw();
  }

  // epilogue: TRANSPOSED emit (d, n) -> (b,h,d,n)
  const int col0 = 768 + j0 + wn * 64;
  const int t3   = col0 / 768;                 // 1=k, 2=v
  const int h    = (col0 - t3 * 768) >> 6;
  __half* dst    = (t3 == 1) ? outK : outV;
  const int m0w  = m0 + wm * 128;
  const int b_   = m0w >> 12;
  const int n0w  = m0w & 4095;
  _Float16* scr  = sh + w * 4096;              // 8KB per wave
  const size_t gbT = (size_t)(b_ * NHEADS + h) * 64 * 4096;

#pragma unroll
  for (int hf = 0; hf < 2; ++hf) {
#pragma unroll
    for (int j = 0; j < 4; ++j) {
      const int col = j * 16 + mrow;           // d
      const float bsv = bias[col0 + col];
#pragma unroll
      for (int ii2 = 0; ii2 < 4; ++ii2)
#pragma unroll
        for (int r = 0; r < 4; ++r) {
          const int row = ii2 * 16 + quad * 4 + r;   // n-local
          float val = acc[hf * 4 + ii2][j][r] + bsv;
          if (t3 == 1) val = (val > 0.f) ? (val + 1.f) : expf(val);  // elu+1
          write_l64(scr, col, row, val);             // (d, n)
        }
    }
    barrier_raw();
#pragma unroll
    for (int it = 0; it < 8; ++it) {
      const int dd = it * 8 + (l >> 3);
      const int c  = l & 7;
      half8 vv = read_l64c(scr, dd, c);
      *(half8*)((_Float16*)dst + gbT + (size_t)dd * 4096 + n0w + hf * 64 + c * 8) = vv;
    }
    barrier_raw();
  }
}

// ====== proj HGEMM: 128x128 tile, 3-deep ring, 3 blk/CU (R6, unchanged) ====
__global__ __launch_bounds__(256, 3) void hgemm_proj_kernel(
    const __half* __restrict__ A, const __half* __restrict__ W,
    const float* __restrict__ bias, float* __restrict__ outF)
{
  const int K = 768;
  const int NT = 24;
  __shared__ __align__(16) _Float16 sh[3 * 8192];   // 48KB: 3 slots x (A | B)
  const int t    = threadIdx.x;
  const int w    = t >> 6;
  const int l    = t & 63;
  const int quad = l >> 4;
  const int mrow = l & 15;
  const int wr   = (w >> 1) * 64;
  const int wc   = (w & 1) * 64;

  const int bid  = blockIdx.x;
  const int xcd  = bid & 7;
  const int ii   = bid >> 3;               // 0..191
  const int mg   = ii / 6;                 // 0..31
  const int jj   = ii - mg * 6;            // 0..5
  const int m0   = (xcd * 32 + mg) * 128;
  const int j0   = jj * 128;

  const int s1  = 256 + t;
  const int mpa = t >> 3,  ppa = (t & 7) ^ (mpa & 7);
  const int ra  = mpa * 2 + (ppa >> 2), qa = (ppa & 3) * 8;
  const int mpb = s1 >> 3, ppb = (s1 & 7) ^ (mpb & 7);
  const int rb  = mpb * 2 + (ppb >> 2), qb = (ppb & 3) * 8;
  const int lda_ = (t >> 6) * 512;          // wave-uniform
  const int ldb_ = (s1 >> 6) * 512;
  const __half* gA_0 = A + (size_t)(m0 + ra) * K + qa;
  const __half* gA_1 = A + (size_t)(m0 + rb) * K + qb;
  const __half* gB_0 = W + (size_t)(j0 + ra) * K + qa;
  const __half* gB_1 = W + (size_t)(j0 + rb) * K + qb;

  int aoff[4], boff[4];
#pragma unroll
  for (int i = 0; i < 4; ++i) aoff[i] = fragoff(wr + i * 16 + mrow, quad);
#pragma unroll
  for (int j = 0; j < 4; ++j) boff[j] = 4096 + fragoff(wc + j * 16 + mrow, quad);

  floatx4 acc[4][4];
#pragma unroll
  for (int i = 0; i < 4; ++i)
#pragma unroll
    for (int j = 0; j < 4; ++j) acc[i][j] = (floatx4){0.f, 0.f, 0.f, 0.f};

  gld16(gA_0, sh + lda_);           gld16(gA_1, sh + ldb_);
  gld16(gB_0, sh + 4096 + lda_);    gld16(gB_1, sh + 4096 + ldb_);
  gld16(gA_0 + 32, sh + 8192 + lda_);        gld16(gA_1 + 32, sh + 8192 + ldb_);
  gld16(gB_0 + 32, sh + 12288 + lda_);       gld16(gB_1 + 32, sh + 12288 + ldb_);
  asm volatile("s_waitcnt vmcnt(4)" ::: "memory");   // tile 0 landed
  barrier_raw();

  int cur = 0, nxt = 2;                    // slot indices (mod 3)
#pragma unroll 3
  for (int kt = 0; kt < NT; ++kt) {
    const _Float16* bb = sh + cur * 8192;
    _Float16* db = sh + nxt * 8192;
    const bool st = (kt + 2 < NT);
    const int kg = (kt + 2) * 32;

    if (st) {
      gld16(gA_0 + kg, db + lda_);        gld16(gA_1 + kg, db + ldb_);
      gld16(gB_0 + kg, db + 4096 + lda_); gld16(gB_1 + kg, db + 4096 + ldb_);
    }
    half8 af[4], bf[4];
#pragma unroll
    for (int i = 0; i < 4; ++i) af[i] = *(const half8*)(bb + aoff[i]);
#pragma unroll
    for (int j = 0; j < 4; ++j) bf[j] = *(const half8*)(bb + boff[j]);
#pragma unroll
    for (int i = 0; i < 4; ++i)
#pragma unroll
      for (int j = 0; j < 4; ++j)
        acc[i][j] = __builtin_amdgcn_mfma_f32_16x16x32_f16(af[i], bf[j], acc[i][j], 0, 0, 0);

    if (kt < NT - 2)       asm volatile("s_waitcnt vmcnt(4)" ::: "memory");
    else if (kt == NT - 2) asm volatile("s_waitcnt vmcnt(0)" ::: "memory");
    barrier_raw();
    cur = (cur + 1) % 3;
    nxt = (nxt + 1) % 3;
  }

#pragma unroll
  for (int j = 0; j < 4; ++j) {
    const int col = j0 + wc + j * 16 + mrow;
    const float bsv = bias[col];
#pragma unroll
    for (int i = 0; i < 4; ++i)
#pragma unroll
      for (int r = 0; r < 4; ++r) {
        const int m = m0 + wr + i * 16 + quad * 4 + r;
        outF[(size_t)m * 768 + col] = acc[i][j][r] + bsv;
      }
  }
}

// ============ kv via MFMA on transposed k,v: no LDS staging (unchanged) ====
__global__ __launch_bounds__(256) void kv_mfma_kernel(
    const __half* __restrict__ kT, const __half* __restrict__ vT,
    float* __restrict__ kv, float* __restrict__ ksum)
{
  extern __shared__ float red[];               // 4*4096 + 4*64 floats
  float* ksr = red + 4 * 4096;
  const int bh = blockIdx.x;                   // 0..95
  const int sp = blockIdx.y;                   // 0..3
  const int t  = threadIdx.x;
  const int w  = t >> 6;
  const int l  = t & 63;
  const int quad = l >> 4;
  const int mrow = l & 15;
  const size_t base = (size_t)bh * 64 * 4096;
  const int n0 = sp * 1024 + w * 256;

  floatx4 acc[4][4];
  floatx4 ks[4];
#pragma unroll
  for (int i = 0; i < 4; ++i) {
    ks[i] = (floatx4){0.f, 0.f, 0.f, 0.f};
#pragma unroll
    for (int j = 0; j < 4; ++j) acc[i][j] = (floatx4){0.f, 0.f, 0.f, 0.f};
  }
  half8 ones;
#pragma unroll
  for (int e = 0; e < 8; ++e) ones[e] = (_Float16)1.0f;

  const __half* pk[4];
  const __half* pv[4];
#pragma unroll
  for (int i = 0; i < 4; ++i) {
    pk[i] = kT + base + (size_t)(i * 16 + mrow) * 4096 + n0 + quad * 8;
    pv[i] = vT + base + (size_t)(i * 16 + mrow) * 4096 + n0 + quad * 8;
  }

#pragma unroll
  for (int nn = 0; nn < 256; nn += 32) {
    half8 af[4], bf[4];
#pragma unroll
    for (int i = 0; i < 4; ++i) af[i] = *(const half8*)(pk[i] + nn);
#pragma unroll
    for (int j = 0; j < 4; ++j) bf[j] = *(const half8*)(pv[j] + nn);
#pragma unroll
    for (int i = 0; i < 4; ++i)
#pragma unroll
      for (int j = 0; j < 4; ++j)
        acc[i][j] = __builtin_amdgcn_mfma_f32_16x16x32_f16(af[i], bf[j], acc[i][j], 0, 0, 0);
#pragma unroll
    for (int i = 0; i < 4; ++i)
      ks[i] = __builtin_amdgcn_mfma_f32_16x16x32_f16(af[i], ones, ks[i], 0, 0, 0);
  }

  float* rw = red + w * 4096;
#pragma unroll
  for (int i = 0; i < 4; ++i)
#pragma unroll
    for (int j = 0; j < 4; ++j)
#pragma unroll
      for (int r = 0; r < 4; ++r)
        rw[(i * 16 + quad * 4 + r) * 64 + j * 16 + mrow] = acc[i][j][r];
  if (mrow == 0) {
#pragma unroll
    for (int i = 0; i < 4; ++i)
#pragma unroll
      for (int r = 0; r < 4; ++r)
        ksr[w * 64 + i * 16 + quad * 4 + r] = ks[i][r];
  }
  __syncthreads();
#pragma unroll
  for (int ii = 0; ii < 16; ++ii) {
    const int idx = ii * 256 + t;
    const float s = red[idx] + red[4096 + idx] + red[8192 + idx] + red[12288 + idx];
    atomicAdd(&kv[(size_t)bh * 4096 + idx], s);
  }
  if (t < 64)
    atomicAdd(&ksum[(size_t)bh * 64 + t], ksr[t] + ksr[64 + t] + ksr[128 + t] + ksr[192 + t]);
}

// ------- fused Q-GEMM + attention apply: 256x128 tile, 4-deep ring -------
// 512 thr = 8 waves (4M x 2N), per-wave 64(n) x 64(d) via acc[4][4].
// Ring: 4 slots x (A 256x32 = 8192 halfs x2units | B 128x32 = 4096) = 96KB.
// One barrier + counted vmcnt(6) per K-tile (R2-proven loose schedule).
// kvT (2 heads, f16 L64) + ksums staged once. Epilogue wave-local with
// explicit lgkmcnt fences (no block barriers needed; per-wave scratch).
__global__ __launch_bounds__(512, 2) void qattn_kernel(
    const __half* __restrict__ A, const __half* __restrict__ W,
    const float* __restrict__ bias,
    const float* __restrict__ kvg, const float* __restrict__ ksumg,
    __half* __restrict__ att)
{
  const int K = 768;
  const int NT = 24;
  extern __shared__ __align__(16) _Float16 sh[];  // 96KB ring + 16KB kvT = 112KB
  __shared__ float norms[512];
  __shared__ float ksums[128];
  const int t    = threadIdx.x;
  const int w    = t >> 6;
  const int l    = t & 63;
  const int quad = l >> 4;
  const int mrow = l & 15;
  const int wr   = (w >> 1) * 64;          // 0,64,128,192 (n within tile)
  const int hh   = w & 1;                  // head half
  const int wc   = hh * 64;

  // XCD-aware, A-reuse-major: 768 blocks = 8 xcd * 16 mg * 6 j
  const int bid = blockIdx.x;
  const int xcd = bid & 7;
  const int ii  = bid >> 3;                // 0..95
  const int mg  = ii / 6;                  // 0..15
  const int jj  = ii - mg * 6;             // 0..5
  const int m0  = (xcd * 16 + mg) * 256;
  const int j0  = jj * 128;
  const int b_  = m0 >> 12;
  const int h0  = jj * 2;

  _Float16* kvT0 = sh + 49152;             // after 4 x 12288 ring slots

  // stage kvT (f16 L64 [e][d], 2 heads) + ksums
#pragma unroll
  for (int it = 0; it < 16; ++it) {
    const int gidx = it * 512 + t;         // 0..8191
    const int head = gidx >> 12;
    const int r    = gidx & 4095;          // d*64+e
    const float val = kvg[(size_t)(b_ * NHEADS + h0 + head) * 4096 + r];
    write_l64(kvT0 + head * 4096, r & 63, r >> 6, val);
  }
  if (t < 128) ksums[t] = ksumg[(size_t)(b_ * NHEADS + h0 + (t >> 6)) * 64 + (t & 63)];

  // hoisted stage addressing (1 load/thread per 128x32 unit; 3 units/K-tile)
  const int mp  = t >> 3;
  const int pp  = (t & 7) ^ (mp & 7);
  const int rsw = mp * 2 + (pp >> 2);
  const int qsw = (pp & 3) * 8;
  const __half* gA0 = A + (size_t)(m0 + rsw) * K + qsw;
  const __half* gA1 = gA0 + (size_t)128 * K;
  const __half* gB0 = W + (size_t)(j0 + rsw) * K + qsw;
  const int ld = (t >> 6) * 512;           // wave-uniform LDS dst (halfs)

  int aoff[4], boff[4];
#pragma unroll
  for (int i = 0; i < 4; ++i) {
    const int rowi = wr + i * 16 + mrow;   // 0..255
    aoff[i] = (rowi >> 7) * 4096 + fragoff(rowi & 127, quad);
  }
#pragma unroll
  for (int j = 0; j < 4; ++j) boff[j] = 8192 + fragoff(wc + j * 16 + mrow, quad);

  floatx4 acc[4][4];
#pragma unroll
  for (int i = 0; i < 4; ++i)
#pragma unroll
    for (int j = 0; j < 4; ++j) acc[i][j] = (floatx4){0.f, 0.f, 0.f, 0.f};

  // prologue: stage K-tiles 0,1,2 (3 loads each)
#pragma unroll
  for (int kt = 0; kt < 3; ++kt) {
    _Float16* db = sh + kt * 12288;
    const int kg = kt * 32;
    gld16(gA0 + kg, db + ld);
    gld16(gA1 + kg, db + 4096 + ld);
    gld16(gB0 + kg, db + 8192 + ld);
  }
  asm volatile("s_waitcnt vmcnt(6)" ::: "memory");   // K-tile 0 landed
  barrier_raw();

#pragma unroll 4
  for (int kt = 0; kt < NT; ++kt) {
    const _Float16* bb = sh + (kt & 3) * 12288;
    const bool st = (kt + 3 < NT);
    _Float16* db = sh + ((kt + 3) & 3) * 12288;
    const int kg = (kt + 3) * 32;
    half8 af[4], bf[4];

#pragma unroll
    for (int j = 0; j < 4; ++j) bf[j] = *(const half8*)(bb + boff[j]);
#pragma unroll
    for (int i = 0; i < 4; ++i) af[i] = *(const half8*)(bb + aoff[i]);
    if (st) {
      gld16(gA0 + kg, db + ld);
      gld16(gA1 + kg, db + 4096 + ld);
      gld16(gB0 + kg, db + 8192 + ld);
    }
#pragma unroll
    for (int i = 0; i < 4; ++i)
#pragma unroll
      for (int j = 0; j < 4; ++j)
        acc[i][j] = __builtin_amdgcn_mfma_f32_16x16x32_f16(af[i], bf[j], acc[i][j], 0, 0, 0);

    if (kt < NT - 3)       asm volatile("s_waitcnt vmcnt(6)" ::: "memory");
    else if (kt == NT - 3) asm volatile("s_waitcnt vmcnt(3)" ::: "memory");
    else if (kt == NT - 2) asm volatile("s_waitcnt vmcnt(0)" ::: "memory");
    barrier_raw();
  }

  // ---- epilogue (wave-local; ring LDS reads all done past final barrier) ----
  _Float16* qtile = sh + w * 4096;         // 8KB/wave within ring region

  // phase 1: q = elu(acc+bias)+1 -> f16 L64
#pragma unroll
  for (int j = 0; j < 4; ++j) {
    const int col = j * 16 + mrow;         // d
    const float bsv = bias[j0 + wc + col];
#pragma unroll
    for (int i = 0; i < 4; ++i)
#pragma unroll
      for (int r = 0; r < 4; ++r) {
        const int row = i * 16 + quad * 4 + r;
        float val = acc[i][j][r] + bsv;
        val = (val > 0.f) ? (val + 1.f) : expf(val);
        write_l64(qtile, row, col, val);
      }
  }
  asm volatile("s_waitcnt lgkmcnt(0)" ::: "memory");
  __builtin_amdgcn_sched_barrier(0);

  // phase 2: reciprocal normalizer (lane l -> row l)
  {
    float nrm = 0.f;
#pragma unroll
    for (int c = 0; c < 8; ++c) {
      half8 qv = read_l64c(qtile, l, c);
#pragma unroll
      for (int e = 0; e < 8; ++e) nrm += (float)qv[e] * ksums[hh * 64 + c * 8 + e];
    }
    norms[w * 64 + l] = 1.f / (nrm + 1e-6f);
  }

  // phase 3: att = q @ kvT^T (k-dim = d = 64)
  const _Float16* kvT = kvT0 + hh * 4096;
  floatx4 oacc[4][4];
#pragma unroll
  for (int i = 0; i < 4; ++i)
#pragma unroll
    for (int j = 0; j < 4; ++j) oacc[i][j] = (floatx4){0.f, 0.f, 0.f, 0.f};
#pragma unroll
  for (int ks = 0; ks < 2; ++ks) {
    half8 af2[4], bf2[4];
#pragma unroll
    for (int i = 0; i < 4; ++i) af2[i] = read_l64c(qtile, i * 16 + mrow, ks * 4 + quad);
#pragma unroll
    for (int j = 0; j < 4; ++j) bf2[j] = read_l64c(kvT, j * 16 + mrow, ks * 4 + quad);
#pragma unroll
    for (int i = 0; i < 4; ++i)
#pragma unroll
      for (int j = 0; j < 4; ++j)
        oacc[i][j] = __builtin_amdgcn_mfma_f32_16x16x32_f16(af2[i], bf2[j], oacc[i][j], 0, 0, 0);
  }
  asm volatile("s_waitcnt lgkmcnt(0)" ::: "memory");
  __builtin_amdgcn_sched_barrier(0);

  // phase 4: scale by 1/norm, transpose via qtile, coalesced store
#pragma unroll
  for (int i = 0; i < 4; ++i)
#pragma unroll
    for (int r = 0; r < 4; ++r) {
      const int row = i * 16 + quad * 4 + r;
      const float rn = norms[w * 64 + row];
#pragma unroll
      for (int j = 0; j < 4; ++j)
        write_l64(qtile, row, j * 16 + mrow, oacc[i][j][r] * rn);
    }
  asm volatile("s_waitcnt lgkmcnt(0)" ::: "memory");
  __builtin_amdgcn_sched_barrier(0);

  const int n0w = (m0 & 4095) + wr;
  const size_t abase = (size_t)(b_ * SEQ + n0w) * 768 + (h0 + hh) * 64;
#pragma unroll
  for (int it = 0; it < 8; ++it) {
    const int row = it * 8 + (l >> 3);
    const int c   = l & 7;
    half8 vv = read_l64c(qtile, row, c);
    *(half8*)((_Float16*)att + abase + (size_t)row * 768 + c * 8) = vv;
  }
}

extern "C" void kernel_launch(void* const* d_in, const int* in_sizes, int n_in,
                              void* d_out, int out_size, void* d_ws, size_t ws_size,
                              hipStream_t stream)
{
  const float* x     = (const float*)d_in[0];
  const float* Wqkv  = (const float*)d_in[1];
  const float* bqkv  = (const float*)d_in[2];
  const float* Wproj = (const float*)d_in[3];
  const float* bproj = (const float*)d_in[4];
  float* out = (float*)d_out;

  const size_t SZ = (size_t)BATCH * NHEADS * SEQ * 64;  // 25,165,824
  __half* xh  = (__half*)d_ws;
  __half* Wqh = xh + SZ;
  __half* Wph = Wqh + (size_t)2304 * 768;
  __half* R3  = Wph + (size_t)768 * 768;   // kT -> att
  __half* R4  = R3 + SZ;                   // vT
  float*  kvb = (float*)(R4 + SZ);
  float*  ksum = kvb + 96 * 64 * 64;

  static bool attr_set = false;
  if (!attr_set) {
    hipFuncSetAttribute((const void*)hgemm_kv8_kernel,
                        hipFuncAttributeMaxDynamicSharedMemorySize, 131072);
    hipFuncSetAttribute((const void*)kv_mfma_kernel,
                        hipFuncAttributeMaxDynamicSharedMemorySize, 66560);
    hipFuncSetAttribute((const void*)qattn_kernel,
                        hipFuncAttributeMaxDynamicSharedMemorySize, 114688);
    attr_set = true;
  }

  zero_kernel<<<1560, 256, 0, stream>>>(kvb, 96 * 64 * 64 + 96 * 64);

  cast_f2h<<<(int)(SZ / 1024), 256, 0, stream>>>(x, xh, (int)SZ);
  cast_f2h<<<(2304 * 768) / 1024, 256, 0, stream>>>(Wqkv, Wqh, 2304 * 768);
  cast_f2h<<<(768 * 768) / 1024, 256, 0, stream>>>(Wproj, Wph, 768 * 768);

  // K,V columns [768, 2304): kT -> R3, vT -> R4, layout (b,h,d,n).
  hgemm_kv8_kernel<<<768, 512, 131072, stream>>>(xh, Wqh, bqkv, R3, R4);

  // kv + ksum via MFMA on the transposed layout
  kv_mfma_kernel<<<dim3(96, 4), 256, 66560, stream>>>(R3, R4, kvb, ksum);

  // fused Q-GEMM + attention: att -> R3 (kT dead after kv_mfma_kernel)
  // 768 blocks (8 xcd x 16 mg x 6 j), 256x128 tile, 4-deep ring.
  qattn_kernel<<<768, 512, 114688, stream>>>(
      xh, Wqh, bqkv, kvb, ksum, R3);

  // output projection: fp32 out, 128x128 3-ring, 3 blk/CU, 1536 blocks
  hgemm_proj_kernel<<<1536, 256, 0, stream>>>(R3, Wph, bproj, out);
}

// Round 8
// 430.923 us; speedup vs baseline: 1.0378x; 1.0270x over previous
//
#include <hip/hip_runtime.h>
#include <hip/hip_fp16.h>
#include <math.h>

#define NHEADS 12
#define SEQ 4096
#define BATCH 8

typedef _Float16 half8 __attribute__((ext_vector_type(8)));
typedef float floatx4 __attribute__((ext_vector_type(4)));

// ---------------- zero small accumulators ----------------
__global__ void zero_kernel(float* p, int n) {
  int i = blockIdx.x * 256 + threadIdx.x;
  if (i < n) p[i] = 0.f;
}

// ---------------- fp32 -> fp16 cast, 4 elems/thread ----------------
__global__ void cast_f2h(const float* __restrict__ in, __half* __restrict__ out, int n) {
  int i = (blockIdx.x * 256 + threadIdx.x) * 4;
  if (i < n) {
    float4 v = *(const float4*)&in[i];
    ushort4 o;
    o.x = __half_as_ushort(__float2half(v.x));
    o.y = __half_as_ushort(__float2half(v.y));
    o.z = __half_as_ushort(__float2half(v.z));
    o.w = __half_as_ushort(__float2half(v.w));
    *(ushort4*)&out[i] = o;
  }
}

// ---- raw 16B global->LDS (dst must be wave-uniform; g carries swizzle) ----
__device__ __forceinline__ void gld16(const __half* g, _Float16* dst) {
  __builtin_amdgcn_global_load_lds((const __attribute__((address_space(1))) void*)g,
                                   (__attribute__((address_space(3))) void*)dst, 16, 0, 0);
}

// fragment LDS offset (halfs) for the staged XOR-swizzle layout
__device__ __forceinline__ int fragoff(int row, int quad) {
  const int mp = row >> 1;
  const int p  = ((row & 1) << 2) | quad;
  return (mp * 8 + (p ^ (mp & 7))) * 8;
}

// ---- L64: 64x64 f16 tile, row-major with XOR swizzle on 16B chunks ----
__device__ __forceinline__ void write_l64(_Float16* lds, int row, int col, float v) {
  lds[row * 64 + ((((col >> 3) ^ (row & 7))) << 3) + (col & 7)] = (_Float16)v;
}
__device__ __forceinline__ half8 read_l64c(const _Float16* lds, int row, int c) {
  return *(const half8*)(lds + row * 64 + ((c ^ (row & 7)) << 3));
}

__device__ __forceinline__ void barrier_raw() {
  asm volatile("s_barrier" ::: "memory");
}

// ====== KV HGEMM: 256x256, BK=64, TRUE 8-phase schedule (m201 port) ======
// 512 thr = 8 waves (2M x 4N), per-wave 128x64, acc[8][4].
// LDS: 2 dbuf x (A 256x64 | B 256x64) = 2 x 64KB = 128KB.
// Units (128 rows x 32 k, 4096 halfs): A u0..u3 = (rows0/128, ksub0/1),
// B likewise at +16384. 4 phases/K-tile, each: {vmcnt if ksub boundary |
// barrier | frag ds_reads | 2 gld16 stages | barrier | setprio 16 MFMA}.
// vmcnt(4) counted (never 0 in steady state): waited loads issued >=2
// phases (~600cy) earlier. Transposed (b,h,d,n) k/v emit.
__global__ __launch_bounds__(512, 2) void hgemm_kv8_kernel(
    const __half* __restrict__ A, const __half* __restrict__ W,
    const float* __restrict__ bias,
    __half* __restrict__ outK, __half* __restrict__ outV)
{
  const int K = 768;
  const int NKT = 12;                      // 768 / 64
  extern __shared__ __align__(16) _Float16 sh[];   // 2 x 32768 halfs = 128KB
  const int t    = threadIdx.x;
  const int w    = t >> 6;
  const int l    = t & 63;
  const int quad = l >> 4;
  const int mrow = l & 15;
  const int wm   = w >> 2;                 // 0..1 (M)
  const int wn   = w & 3;                  // 0..3 (N)

  // XCD-aware, A-reuse-major: j innermost per XCD chunk (FETCH-proven)
  const int bid  = blockIdx.x;
  const int xcd  = bid & 7;
  const int ii   = bid >> 3;               // 0..95
  const int mg   = ii / 6;                 // 0..15
  const int jj   = ii - mg * 6;            // 0..5
  const int m0   = (xcd * 16 + mg) * 256;
  const int j0   = jj * 256;

  // hoisted stage addressing
  const int mp  = t >> 3;
  const int pp  = (t & 7) ^ (mp & 7);
  const int rsw = mp * 2 + (pp >> 2);
  const int qsw = (pp & 3) * 8;
  const __half* gA0 = A + (size_t)(m0 + rsw) * K + qsw;
  const __half* gA1 = gA0 + (size_t)128 * K;
  const __half* gW0 = W + (size_t)(768 + j0 + rsw) * K + qsw;
  const __half* gW1 = gW0 + (size_t)128 * K;
  const int ld = (t >> 6) * 512;           // wave-uniform LDS dst (halfs)

  // fragment offsets: ksub0 / ksub1 variants
  int aoff0[8], aoff1[8], boff0[4], boff1[4];
#pragma unroll
  for (int i = 0; i < 8; ++i) {
    const int fo = fragoff(i * 16 + mrow, quad);
    aoff0[i] = wm * 4096 + fo;             // A unit wm   (ksub0)
    aoff1[i] = (2 + wm) * 4096 + fo;       // A unit 2+wm (ksub1)
  }
#pragma unroll
  for (int j = 0; j < 4; ++j) {
    const int C  = wn * 64 + j * 16 + mrow;
    const int fo = fragoff(C & 127, quad);
    boff0[j] = 16384 + (C >> 7) * 4096 + fo;
    boff1[j] = 16384 + (2 + (C >> 7)) * 4096 + fo;
  }

  floatx4 acc[8][4];
#pragma unroll
  for (int i = 0; i < 8; ++i)
#pragma unroll
    for (int j = 0; j < 4; ++j) acc[i][j] = (floatx4){0.f, 0.f, 0.f, 0.f};

  // prologue: K-tile 0's 8 units in steady-state issue order
  gld16(gA0,      sh + ld);                // A u0 (ksub0)
  gld16(gA1,      sh + 4096  + ld);        // A u1
  gld16(gW0,      sh + 16384 + ld);        // B u0
  gld16(gW1,      sh + 20480 + ld);        // B u1
  gld16(gA0 + 32, sh + 8192  + ld);        // A u2 (ksub1)
  gld16(gA1 + 32, sh + 12288 + ld);        // A u3
  gld16(gW0 + 32, sh + 24576 + ld);        // B u2
  gld16(gW1 + 32, sh + 28672 + ld);        // B u3

#pragma unroll 2
  for (int kt = 0; kt < NKT; ++kt) {
    const _Float16* bb = sh + (kt & 1) * 32768;
    _Float16* db = sh + ((kt + 1) & 1) * 32768;
    const bool st = (kt + 1 < NKT);
    const int kg = (kt + 1) * 64;
    half8 af[4], bf[4];

    // ---- phase 0: ksub0, A rows wm*128 + 0..63 ----
    asm volatile("s_waitcnt vmcnt(4)" ::: "memory");   // ksub0 units landed
    barrier_raw();
#pragma unroll
    for (int j = 0; j < 4; ++j) bf[j] = *(const half8*)(bb + boff0[j]);
#pragma unroll
    for (int i = 0; i < 4; ++i) af[i] = *(const half8*)(bb + aoff0[i]);
    if (st) { gld16(gA0 + kg, db + ld); gld16(gA1 + kg, db + 4096 + ld); }
    barrier_raw();
    __builtin_amdgcn_s_setprio(1);
#pragma unroll
    for (int i = 0; i < 4; ++i)
#pragma unroll
      for (int j = 0; j < 4; ++j)
        acc[i][j] = __builtin_amdgcn_mfma_f32_16x16x32_f16(af[i], bf[j], acc[i][j], 0, 0, 0);
    __builtin_amdgcn_s_setprio(0);

    // ---- phase 1: ksub0, rows 64..127 ----
    barrier_raw();
#pragma unroll
    for (int i = 0; i < 4; ++i) af[i] = *(const half8*)(bb + aoff0[i + 4]);
    if (st) { gld16(gW0 + kg, db + 16384 + ld); gld16(gW1 + kg, db + 20480 + ld); }
    barrier_raw();
    __builtin_amdgcn_s_setprio(1);
#pragma unroll
    for (int i = 0; i < 4; ++i)
#pragma unroll
      for (int j = 0; j < 4; ++j)
        acc[i + 4][j] = __builtin_amdgcn_mfma_f32_16x16x32_f16(af[i], bf[j], acc[i + 4][j], 0, 0, 0);
    __builtin_amdgcn_s_setprio(0);

    // ---- phase 2: ksub1, rows 0..63 ----
    if (st) asm volatile("s_waitcnt vmcnt(4)" ::: "memory");   // ksub1 units landed
    else    asm volatile("s_waitcnt vmcnt(0)" ::: "memory");
    barrier_raw();
#pragma unroll
    for (int j = 0; j < 4; ++j) bf[j] = *(const half8*)(bb + boff1[j]);
#pragma unroll
    for (int i = 0; i < 4; ++i) af[i] = *(const half8*)(bb + aoff1[i]);
    if (st) { gld16(gA0 + kg + 32, db + 8192 + ld); gld16(gA1 + kg + 32, db + 12288 + ld); }
    barrier_raw();
    __builtin_amdgcn_s_setprio(1);
#pragma unroll
    for (int i = 0; i < 4; ++i)
#pragma unroll
      for (int j = 0; j < 4; ++j)
        acc[i][j] = __builtin_amdgcn_mfma_f32_16x16x32_f16(af[i], bf[j], acc[i][j], 0, 0, 0);
    __builtin_amdgcn_s_setprio(0);

    // ---- phase 3: ksub1, rows 64..127 ----
    barrier_raw();
#pragma unroll
    for (int i = 0; i < 4; ++i) af[i] = *(const half8*)(bb + aoff1[i + 4]);
    if (st) { gld16(gW0 + kg + 32, db + 24576 + ld); gld16(gW1 + kg + 32, db + 28672 + ld); }
    barrier_raw();
    __builtin_amdgcn_s_setprio(1);
#pragma unroll
    for (int i = 0; i < 4; ++i)
#pragma unroll
      for (int j = 0; j < 4; ++j)
        acc[i + 4][j] = __builtin_amdgcn_mfma_f32_16x16x32_f16(af[i], bf[j], acc[i + 4][j], 0, 0, 0);
    __builtin_amdgcn_s_setprio(0);
  }
  barrier_raw();

  // epilogue: wave tile = 128 rows(n) x one head's 64 cols(d) of k or v.
  // TRANSPOSED emit: scratch (d, n), global layout (b,h,d,n).
  const int col0 = 768 + j0 + wn * 64;
  const int t3   = col0 / 768;                 // 1=k, 2=v
  const int h    = (col0 - t3 * 768) >> 6;
  __half* dst    = (t3 == 1) ? outK : outV;
  const int m0w  = m0 + wm * 128;
  const int b_   = m0w >> 12;
  const int n0w  = m0w & 4095;
  _Float16* scr  = sh + w * 4096;              // 8KB per wave
  const size_t gbT = (size_t)(b_ * NHEADS + h) * 64 * 4096;

#pragma unroll
  for (int hf = 0; hf < 2; ++hf) {
#pragma unroll
    for (int j = 0; j < 4; ++j) {
      const int col = j * 16 + mrow;           // d
      const float bsv = bias[col0 + col];
#pragma unroll
      for (int ii2 = 0; ii2 < 4; ++ii2)
#pragma unroll
        for (int r = 0; r < 4; ++r) {
          const int row = ii2 * 16 + quad * 4 + r;   // n-local
          float val = acc[hf * 4 + ii2][j][r] + bsv;
          if (t3 == 1) val = (val > 0.f) ? (val + 1.f) : expf(val);  // elu+1
          write_l64(scr, col, row, val);             // (d, n)
        }
    }
    barrier_raw();
#pragma unroll
    for (int it = 0; it < 8; ++it) {
      const int dd = it * 8 + (l >> 3);
      const int c  = l & 7;
      half8 vv = read_l64c(scr, dd, c);
      *(half8*)((_Float16*)dst + gbT + (size_t)dd * 4096 + n0w + hf * 64 + c * 8) = vv;
    }
    barrier_raw();
  }
}

// ====== proj HGEMM: 128x128 tile, 3-deep ring, 3 blk/CU (unchanged) ====
__global__ __launch_bounds__(256, 3) void hgemm_proj_kernel(
    const __half* __restrict__ A, const __half* __restrict__ W,
    const float* __restrict__ bias, float* __restrict__ outF)
{
  const int K = 768;
  const int NT = 24;
  __shared__ __align__(16) _Float16 sh[3 * 8192];   // 48KB: 3 slots x (A | B)
  const int t    = threadIdx.x;
  const int w    = t >> 6;
  const int l    = t & 63;
  const int quad = l >> 4;
  const int mrow = l & 15;
  const int wr   = (w >> 1) * 64;
  const int wc   = (w & 1) * 64;

  const int bid  = blockIdx.x;
  const int xcd  = bid & 7;
  const int ii   = bid >> 3;               // 0..191
  const int mg   = ii / 6;                 // 0..31
  const int jj   = ii - mg * 6;            // 0..5
  const int m0   = (xcd * 32 + mg) * 128;
  const int j0   = jj * 128;

  const int s1  = 256 + t;
  const int mpa = t >> 3,  ppa = (t & 7) ^ (mpa & 7);
  const int ra  = mpa * 2 + (ppa >> 2), qa = (ppa & 3) * 8;
  const int mpb = s1 >> 3, ppb = (s1 & 7) ^ (mpb & 7);
  const int rb  = mpb * 2 + (ppb >> 2), qb = (ppb & 3) * 8;
  const int lda_ = (t >> 6) * 512;          // wave-uniform
  const int ldb_ = (s1 >> 6) * 512;
  const __half* gA_0 = A + (size_t)(m0 + ra) * K + qa;
  const __half* gA_1 = A + (size_t)(m0 + rb) * K + qb;
  const __half* gB_0 = W + (size_t)(j0 + ra) * K + qa;
  const __half* gB_1 = W + (size_t)(j0 + rb) * K + qb;

  int aoff[4], boff[4];
#pragma unroll
  for (int i = 0; i < 4; ++i) aoff[i] = fragoff(wr + i * 16 + mrow, quad);
#pragma unroll
  for (int j = 0; j < 4; ++j) boff[j] = 4096 + fragoff(wc + j * 16 + mrow, quad);

  floatx4 acc[4][4];
#pragma unroll
  for (int i = 0; i < 4; ++i)
#pragma unroll
    for (int j = 0; j < 4; ++j) acc[i][j] = (floatx4){0.f, 0.f, 0.f, 0.f};

  gld16(gA_0, sh + lda_);           gld16(gA_1, sh + ldb_);
  gld16(gB_0, sh + 4096 + lda_);    gld16(gB_1, sh + 4096 + ldb_);
  gld16(gA_0 + 32, sh + 8192 + lda_);        gld16(gA_1 + 32, sh + 8192 + ldb_);
  gld16(gB_0 + 32, sh + 12288 + lda_);       gld16(gB_1 + 32, sh + 12288 + ldb_);
  asm volatile("s_waitcnt vmcnt(4)" ::: "memory");   // tile 0 landed
  barrier_raw();

  int cur = 0, nxt = 2;                    // slot indices (mod 3)
#pragma unroll 3
  for (int kt = 0; kt < NT; ++kt) {
    const _Float16* bb = sh + cur * 8192;
    _Float16* db = sh + nxt * 8192;
    const bool st = (kt + 2 < NT);
    const int kg = (kt + 2) * 32;

    if (st) {
      gld16(gA_0 + kg, db + lda_);        gld16(gA_1 + kg, db + ldb_);
      gld16(gB_0 + kg, db + 4096 + lda_); gld16(gB_1 + kg, db + 4096 + ldb_);
    }
    half8 af[4], bf[4];
#pragma unroll
    for (int i = 0; i < 4; ++i) af[i] = *(const half8*)(bb + aoff[i]);
#pragma unroll
    for (int j = 0; j < 4; ++j) bf[j] = *(const half8*)(bb + boff[j]);
#pragma unroll
    for (int i = 0; i < 4; ++i)
#pragma unroll
      for (int j = 0; j < 4; ++j)
        acc[i][j] = __builtin_amdgcn_mfma_f32_16x16x32_f16(af[i], bf[j], acc[i][j], 0, 0, 0);

    if (kt < NT - 2)       asm volatile("s_waitcnt vmcnt(4)" ::: "memory");
    else if (kt == NT - 2) asm volatile("s_waitcnt vmcnt(0)" ::: "memory");
    barrier_raw();
    cur = (cur + 1) % 3;
    nxt = (nxt + 1) % 3;
  }

#pragma unroll
  for (int j = 0; j < 4; ++j) {
    const int col = j0 + wc + j * 16 + mrow;
    const float bsv = bias[col];
#pragma unroll
    for (int i = 0; i < 4; ++i)
#pragma unroll
      for (int r = 0; r < 4; ++r) {
        const int m = m0 + wr + i * 16 + quad * 4 + r;
        outF[(size_t)m * 768 + col] = acc[i][j][r] + bsv;
      }
  }
}

// ============ kv via MFMA on transposed k,v: no LDS staging (unchanged) ====
__global__ __launch_bounds__(256) void kv_mfma_kernel(
    const __half* __restrict__ kT, const __half* __restrict__ vT,
    float* __restrict__ kv, float* __restrict__ ksum)
{
  extern __shared__ float red[];               // 4*4096 + 4*64 floats
  float* ksr = red + 4 * 4096;
  const int bh = blockIdx.x;                   // 0..95
  const int sp = blockIdx.y;                   // 0..3
  const int t  = threadIdx.x;
  const int w  = t >> 6;
  const int l  = t & 63;
  const int quad = l >> 4;
  const int mrow = l & 15;
  const size_t base = (size_t)bh * 64 * 4096;
  const int n0 = sp * 1024 + w * 256;

  floatx4 acc[4][4];
  floatx4 ks[4];
#pragma unroll
  for (int i = 0; i < 4; ++i) {
    ks[i] = (floatx4){0.f, 0.f, 0.f, 0.f};
#pragma unroll
    for (int j = 0; j < 4; ++j) acc[i][j] = (floatx4){0.f, 0.f, 0.f, 0.f};
  }
  half8 ones;
#pragma unroll
  for (int e = 0; e < 8; ++e) ones[e] = (_Float16)1.0f;

  const __half* pk[4];
  const __half* pv[4];
#pragma unroll
  for (int i = 0; i < 4; ++i) {
    pk[i] = kT + base + (size_t)(i * 16 + mrow) * 4096 + n0 + quad * 8;
    pv[i] = vT + base + (size_t)(i * 16 + mrow) * 4096 + n0 + quad * 8;
  }

#pragma unroll
  for (int nn = 0; nn < 256; nn += 32) {
    half8 af[4], bf[4];
#pragma unroll
    for (int i = 0; i < 4; ++i) af[i] = *(const half8*)(pk[i] + nn);
#pragma unroll
    for (int j = 0; j < 4; ++j) bf[j] = *(const half8*)(pv[j] + nn);
#pragma unroll
    for (int i = 0; i < 4; ++i)
#pragma unroll
      for (int j = 0; j < 4; ++j)
        acc[i][j] = __builtin_amdgcn_mfma_f32_16x16x32_f16(af[i], bf[j], acc[i][j], 0, 0, 0);
#pragma unroll
    for (int i = 0; i < 4; ++i)
      ks[i] = __builtin_amdgcn_mfma_f32_16x16x32_f16(af[i], ones, ks[i], 0, 0, 0);
  }

  float* rw = red + w * 4096;
#pragma unroll
  for (int i = 0; i < 4; ++i)
#pragma unroll
    for (int j = 0; j < 4; ++j)
#pragma unroll
      for (int r = 0; r < 4; ++r)
        rw[(i * 16 + quad * 4 + r) * 64 + j * 16 + mrow] = acc[i][j][r];
  if (mrow == 0) {
#pragma unroll
    for (int i = 0; i < 4; ++i)
#pragma unroll
      for (int r = 0; r < 4; ++r)
        ksr[w * 64 + i * 16 + quad * 4 + r] = ks[i][r];
  }
  __syncthreads();
#pragma unroll
  for (int ii = 0; ii < 16; ++ii) {
    const int idx = ii * 256 + t;
    const float s = red[idx] + red[4096 + idx] + red[8192 + idx] + red[12288 + idx];
    atomicAdd(&kv[(size_t)bh * 4096 + idx], s);
  }
  if (t < 64)
    atomicAdd(&ksum[(size_t)bh * 64 + t], ksr[t] + ksr[64 + t] + ksr[128 + t] + ksr[192 + t]);
}

// ------- fused Q-GEMM + attention apply: 256x128 ring (R7, unchanged) -------
__global__ __launch_bounds__(512, 2) void qattn_kernel(
    const __half* __restrict__ A, const __half* __restrict__ W,
    const float* __restrict__ bias,
    const float* __restrict__ kvg, const float* __restrict__ ksumg,
    __half* __restrict__ att)
{
  const int K = 768;
  const int NT = 24;
  extern __shared__ __align__(16) _Float16 sh[];  // 96KB ring + 16KB kvT = 112KB
  __shared__ float norms[512];
  __shared__ float ksums[128];
  const int t    = threadIdx.x;
  const int w    = t >> 6;
  const int l    = t & 63;
  const int quad = l >> 4;
  const int mrow = l & 15;
  const int wr   = (w >> 1) * 64;          // 0,64,128,192 (n within tile)
  const int hh   = w & 1;                  // head half
  const int wc   = hh * 64;

  const int bid = blockIdx.x;
  const int xcd = bid & 7;
  const int ii  = bid >> 3;                // 0..95
  const int mg  = ii / 6;                  // 0..15
  const int jj  = ii - mg * 6;             // 0..5
  const int m0  = (xcd * 16 + mg) * 256;
  const int j0  = jj * 128;
  const int b_  = m0 >> 12;
  const int h0  = jj * 2;

  _Float16* kvT0 = sh + 49152;             // after 4 x 12288 ring slots

#pragma unroll
  for (int it = 0; it < 16; ++it) {
    const int gidx = it * 512 + t;         // 0..8191
    const int head = gidx >> 12;
    const int r    = gidx & 4095;          // d*64+e
    const float val = kvg[(size_t)(b_ * NHEADS + h0 + head) * 4096 + r];
    write_l64(kvT0 + head * 4096, r & 63, r >> 6, val);
  }
  if (t < 128) ksums[t] = ksumg[(size_t)(b_ * NHEADS + h0 + (t >> 6)) * 64 + (t & 63)];

  const int mp  = t >> 3;
  const int pp  = (t & 7) ^ (mp & 7);
  const int rsw = mp * 2 + (pp >> 2);
  const int qsw = (pp & 3) * 8;
  const __half* gA0 = A + (size_t)(m0 + rsw) * K + qsw;
  const __half* gA1 = gA0 + (size_t)128 * K;
  const __half* gB0 = W + (size_t)(j0 + rsw) * K + qsw;
  const int ld = (t >> 6) * 512;           // wave-uniform LDS dst (halfs)

  int aoff[4], boff[4];
#pragma unroll
  for (int i = 0; i < 4; ++i) {
    const int rowi = wr + i * 16 + mrow;   // 0..255
    aoff[i] = (rowi >> 7) * 4096 + fragoff(rowi & 127, quad);
  }
#pragma unroll
  for (int j = 0; j < 4; ++j) boff[j] = 8192 + fragoff(wc + j * 16 + mrow, quad);

  floatx4 acc[4][4];
#pragma unroll
  for (int i = 0; i < 4; ++i)
#pragma unroll
    for (int j = 0; j < 4; ++j) acc[i][j] = (floatx4){0.f, 0.f, 0.f, 0.f};

#pragma unroll
  for (int kt = 0; kt < 3; ++kt) {
    _Float16* db = sh + kt * 12288;
    const int kg = kt * 32;
    gld16(gA0 + kg, db + ld);
    gld16(gA1 + kg, db + 4096 + ld);
    gld16(gB0 + kg, db + 8192 + ld);
  }
  asm volatile("s_waitcnt vmcnt(6)" ::: "memory");   // K-tile 0 landed
  barrier_raw();

#pragma unroll 4
  for (int kt = 0; kt < NT; ++kt) {
    const _Float16* bb = sh + (kt & 3) * 12288;
    const bool st = (kt + 3 < NT);
    _Float16* db = sh + ((kt + 3) & 3) * 12288;
    const int kg = (kt + 3) * 32;
    half8 af[4], bf[4];

#pragma unroll
    for (int j = 0; j < 4; ++j) bf[j] = *(const half8*)(bb + boff[j]);
#pragma unroll
    for (int i = 0; i < 4; ++i) af[i] = *(const half8*)(bb + aoff[i]);
    if (st) {
      gld16(gA0 + kg, db + ld);
      gld16(gA1 + kg, db + 4096 + ld);
      gld16(gB0 + kg, db + 8192 + ld);
    }
#pragma unroll
    for (int i = 0; i < 4; ++i)
#pragma unroll
      for (int j = 0; j < 4; ++j)
        acc[i][j] = __builtin_amdgcn_mfma_f32_16x16x32_f16(af[i], bf[j], acc[i][j], 0, 0, 0);

    if (kt < NT - 3)       asm volatile("s_waitcnt vmcnt(6)" ::: "memory");
    else if (kt == NT - 3) asm volatile("s_waitcnt vmcnt(3)" ::: "memory");
    else if (kt == NT - 2) asm volatile("s_waitcnt vmcnt(0)" ::: "memory");
    barrier_raw();
  }

  // ---- epilogue (wave-local) ----
  _Float16* qtile = sh + w * 4096;         // 8KB/wave within ring region

#pragma unroll
  for (int j = 0; j < 4; ++j) {
    const int col = j * 16 + mrow;         // d
    const float bsv = bias[j0 + wc + col];
#pragma unroll
    for (int i = 0; i < 4; ++i)
#pragma unroll
      for (int r = 0; r < 4; ++r) {
        const int row = i * 16 + quad * 4 + r;
        float val = acc[i][j][r] + bsv;
        val = (val > 0.f) ? (val + 1.f) : expf(val);
        write_l64(qtile, row, col, val);
      }
  }
  asm volatile("s_waitcnt lgkmcnt(0)" ::: "memory");
  __builtin_amdgcn_sched_barrier(0);

  {
    float nrm = 0.f;
#pragma unroll
    for (int c = 0; c < 8; ++c) {
      half8 qv = read_l64c(qtile, l, c);
#pragma unroll
      for (int e = 0; e < 8; ++e) nrm += (float)qv[e] * ksums[hh * 64 + c * 8 + e];
    }
    norms[w * 64 + l] = 1.f / (nrm + 1e-6f);
  }

  const _Float16* kvT = kvT0 + hh * 4096;
  floatx4 oacc[4][4];
#pragma unroll
  for (int i = 0; i < 4; ++i)
#pragma unroll
    for (int j = 0; j < 4; ++j) oacc[i][j] = (floatx4){0.f, 0.f, 0.f, 0.f};
#pragma unroll
  for (int ks = 0; ks < 2; ++ks) {
    half8 af2[4], bf2[4];
#pragma unroll
    for (int i = 0; i < 4; ++i) af2[i] = read_l64c(qtile, i * 16 + mrow, ks * 4 + quad);
#pragma unroll
    for (int j = 0; j < 4; ++j) bf2[j] = read_l64c(kvT, j * 16 + mrow, ks * 4 + quad);
#pragma unroll
    for (int i = 0; i < 4; ++i)
#pragma unroll
      for (int j = 0; j < 4; ++j)
        oacc[i][j] = __builtin_amdgcn_mfma_f32_16x16x32_f16(af2[i], bf2[j], oacc[i][j], 0, 0, 0);
  }
  asm volatile("s_waitcnt lgkmcnt(0)" ::: "memory");
  __builtin_amdgcn_sched_barrier(0);

#pragma unroll
  for (int i = 0; i < 4; ++i)
#pragma unroll
    for (int r = 0; r < 4; ++r) {
      const int row = i * 16 + quad * 4 + r;
      const float rn = norms[w * 64 + row];
#pragma unroll
      for (int j = 0; j < 4; ++j)
        write_l64(qtile, row, j * 16 + mrow, oacc[i][j][r] * rn);
    }
  asm volatile("s_waitcnt lgkmcnt(0)" ::: "memory");
  __builtin_amdgcn_sched_barrier(0);

  const int n0w = (m0 & 4095) + wr;
  const size_t abase = (size_t)(b_ * SEQ + n0w) * 768 + (h0 + hh) * 64;
#pragma unroll
  for (int it = 0; it < 8; ++it) {
    const int row = it * 8 + (l >> 3);
    const int c   = l & 7;
    half8 vv = read_l64c(qtile, row, c);
    *(half8*)((_Float16*)att + abase + (size_t)row * 768 + c * 8) = vv;
  }
}

extern "C" void kernel_launch(void* const* d_in, const int* in_sizes, int n_in,
                              void* d_out, int out_size, void* d_ws, size_t ws_size,
                              hipStream_t stream)
{
  const float* x     = (const float*)d_in[0];
  const float* Wqkv  = (const float*)d_in[1];
  const float* bqkv  = (const float*)d_in[2];
  const float* Wproj = (const float*)d_in[3];
  const float* bproj = (const float*)d_in[4];
  float* out = (float*)d_out;

  const size_t SZ = (size_t)BATCH * NHEADS * SEQ * 64;  // 25,165,824
  __half* xh  = (__half*)d_ws;
  __half* Wqh = xh + SZ;
  __half* Wph = Wqh + (size_t)2304 * 768;
  __half* R3  = Wph + (size_t)768 * 768;   // kT -> att
  __half* R4  = R3 + SZ;                   // vT
  float*  kvb = (float*)(R4 + SZ);
  float*  ksum = kvb + 96 * 64 * 64;

  static bool attr_set = false;
  if (!attr_set) {
    hipFuncSetAttribute((const void*)hgemm_kv8_kernel,
                        hipFuncAttributeMaxDynamicSharedMemorySize, 131072);
    hipFuncSetAttribute((const void*)kv_mfma_kernel,
                        hipFuncAttributeMaxDynamicSharedMemorySize, 66560);
    hipFuncSetAttribute((const void*)qattn_kernel,
                        hipFuncAttributeMaxDynamicSharedMemorySize, 114688);
    attr_set = true;
  }

  zero_kernel<<<1560, 256, 0, stream>>>(kvb, 96 * 64 * 64 + 96 * 64);

  cast_f2h<<<(int)(SZ / 1024), 256, 0, stream>>>(x, xh, (int)SZ);
  cast_f2h<<<(2304 * 768) / 1024, 256, 0, stream>>>(Wqkv, Wqh, 2304 * 768);
  cast_f2h<<<(768 * 768) / 1024, 256, 0, stream>>>(Wproj, Wph, 768 * 768);

  // K,V columns [768, 2304): kT -> R3, vT -> R4, layout (b,h,d,n).
  hgemm_kv8_kernel<<<768, 512, 131072, stream>>>(xh, Wqh, bqkv, R3, R4);

  // kv + ksum via MFMA on the transposed layout
  kv_mfma_kernel<<<dim3(96, 4), 256, 66560, stream>>>(R3, R4, kvb, ksum);

  // fused Q-GEMM + attention: att -> R3 (kT dead after kv_mfma_kernel)
  qattn_kernel<<<768, 512, 114688, stream>>>(
      xh, Wqh, bqkv, kvb, ksum, R3);

  // output projection: fp32 out, 128x128 3-ring, 3 blk/CU, 1536 blocks
  hgemm_proj_kernel<<<1536, 256, 0, stream>>>(R3, Wph, bproj, out);
}